// Round 3
// baseline (652.382 us; speedup 1.0000x reference)
//
#include <hip/hip_runtime.h>

#define D 128

// ---------------- bf16 helpers (RTN-even) ----------------
__device__ __forceinline__ unsigned short f2bf(float f) {
  union { float f; unsigned int u; } c; c.f = f;
  unsigned int u = c.u;
  unsigned int r = (u + 0x7fffu + ((u >> 16) & 1u)) >> 16;
  return (unsigned short)r;
}
__device__ __forceinline__ float bf_lo(unsigned int w) {
  return __uint_as_float(w << 16);
}
__device__ __forceinline__ float bf_hi(unsigned int w) {
  return __uint_as_float(w & 0xffff0000u);
}

// ---------------- CSR build ----------------

__global__ void hist_k(const int* __restrict__ dst, int* __restrict__ cnt, int E) {
  int e = blockIdx.x * blockDim.x + threadIdx.x;
  if (e < E) atomicAdd(&cnt[dst[e]], 1);
}

__device__ void exscan_dev(int* cnt_cursor, int* rp, int n) {
  __shared__ int wsum[16];
  __shared__ int carry_s;
  const int tid = threadIdx.x;
  const int lane = tid & 63, wid = tid >> 6;
  if (tid == 0) carry_s = 0;
  __syncthreads();
  for (int base = 0; base < n; base += 1024) {
    int idx = base + tid;
    int v = (idx < n) ? cnt_cursor[idx] : 0;
    int s = v;
#pragma unroll
    for (int ofs = 1; ofs < 64; ofs <<= 1) {
      int t = __shfl_up(s, ofs);
      if (lane >= ofs) s += t;
    }
    if (lane == 63) wsum[wid] = s;
    __syncthreads();
    if (wid == 0) {
      int ws = (lane < 16) ? wsum[lane] : 0;
#pragma unroll
      for (int ofs = 1; ofs < 16; ofs <<= 1) {
        int t = __shfl_up(ws, ofs);
        if (lane >= ofs) ws += t;
      }
      if (lane < 16) wsum[lane] = ws;
    }
    __syncthreads();
    int pre = (wid > 0) ? wsum[wid - 1] : 0;
    int carry = carry_s;
    int ex = carry + pre + s - v;
    if (idx < n) { rp[idx] = ex; cnt_cursor[idx] = ex; }
    __syncthreads();
    if (tid == 1023) carry_s = carry + wsum[15];
    __syncthreads();
  }
  if (tid == 0) rp[n] = carry_s;
}

__global__ void exscan2_k(int* c1, int* r1, int* c2, int* r2, int n) {
  if (blockIdx.x == 0) exscan_dev(c1, r1, n);
  else exscan_dev(c2, r2, n);
}

__global__ void fill_k(const int* __restrict__ src, const int* __restrict__ dst,
                       int* __restrict__ cursor, int* __restrict__ srcs, int E) {
  int e = blockIdx.x * blockDim.x + threadIdx.x;
  if (e < E) {
    int pos = atomicAdd(&cursor[dst[e]], 1);
    srcs[pos] = src[e];
  }
}

// ---------------- weight precompute ----------------
__global__ __launch_bounds__(128) void mk_M(const float* __restrict__ Wq,
                                            const float* __restrict__ Wk,
                                            float* __restrict__ M) {
  int r = blockIdx.x, c = threadIdx.x;
  float acc = 0.f;
  for (int d = 0; d < D; ++d) acc += Wq[r * D + d] * Wk[c * D + d];
  M[r * D + c] = acc;
}

__global__ __launch_bounds__(256) void mk_Wcat(const float* __restrict__ W0,
                                               const float* __restrict__ W1,
                                               const float* __restrict__ Wv,
                                               float* __restrict__ Wc) {
  int idx = blockIdx.x * blockDim.x + threadIdx.x;
  if (idx >= 384 * D) return;
  int r = idx >> 7, c = idx & 127;
  float v;
  if (r < 128) v = W0[r * D + c];
  else if (r < 256) v = W1[(r - 128) * D + c];
  else v = -Wv[(r - 256) * D + c];
  Wc[idx] = v;
}

__global__ __launch_bounds__(128) void mk_WM(const float* __restrict__ Wc,
                                             const float* __restrict__ M,
                                             float* __restrict__ WM) {
  int r = blockIdx.x, c = threadIdx.x;
  float acc = 0.f;
  for (int k = 0; k < D; ++k) acc += Wc[r * D + k] * M[k * D + c];
  WM[r * D + c] = acc;
}

// x -> bf16 copy
__global__ __launch_bounds__(256) void cvt_k(const float* __restrict__ x,
                                             unsigned short* __restrict__ hb, int n4) {
  int i = blockIdx.x * blockDim.x + threadIdx.x;
  if (i >= n4) return;
  float4 v = *(const float4*)&x[i * 4];
  ushort4 o;
  o.x = f2bf(v.x); o.y = f2bf(v.y); o.z = f2bf(v.z); o.w = f2bf(v.w);
  *(ushort4*)&hb[i * 4] = o;
}

// ---------------- gather/aggregate: one wave per node, bf16 neighbor rows ----------------
__device__ __forceinline__ float wave_reduce_sum(float v) {
  v += __shfl_xor(v, 32);
  v += __shfl_xor(v, 16);
  v += __shfl_xor(v, 8);
  v += __shfl_xor(v, 4);
  v += __shfl_xor(v, 2);
  v += __shfl_xor(v, 1);
  return v;
}

__global__ __launch_bounds__(256) void agg_k(
    const unsigned short* __restrict__ hb,          // N x 128 bf16
    const float* __restrict__ qt, int ldqt,         // Qt rows (fp32)
    const int* __restrict__ rp1, const int* __restrict__ s1,
    const int* __restrict__ rp2, const int* __restrict__ s2,
    float* __restrict__ G, int N) {
  int gw = (int)((blockIdx.x * blockDim.x + threadIdx.x) >> 6);
  if (gw >= N) return;
  const int i = __builtin_amdgcn_readfirstlane(gw);
  const int l = threadIdx.x & 63;
  const int f = 2 * l;

  float2 q = *(const float2*)&qt[(size_t)i * ldqt + f];
  float2 a1 = make_float2(0.f, 0.f);
  float2 a2 = make_float2(0.f, 0.f);

  // TAGConv neighbor sum
  int e = rp1[i], end = rp1[i + 1];
  for (; e + 8 <= end; e += 8) {
    unsigned int w[8];
#pragma unroll
    for (int u = 0; u < 8; ++u) {
      int j = s1[e + u];
      w[u] = *(const unsigned int*)&hb[(size_t)j * D + f];
    }
#pragma unroll
    for (int u = 0; u < 8; ++u) { a1.x += bf_lo(w[u]); a1.y += bf_hi(w[u]); }
  }
  for (; e < end; ++e) {
    int j = s1[e];
    unsigned int w = *(const unsigned int*)&hb[(size_t)j * D + f];
    a1.x += bf_lo(w); a1.y += bf_hi(w);
  }

  // attention aggregate
  e = rp2[i]; end = rp2[i + 1];
  for (; e + 4 <= end; e += 4) {
    float2 v[4]; float p[4];
#pragma unroll
    for (int u = 0; u < 4; ++u) {
      int j = s2[e + u];
      unsigned int w = *(const unsigned int*)&hb[(size_t)j * D + f];
      v[u] = make_float2(bf_lo(w), bf_hi(w));
    }
#pragma unroll
    for (int u = 0; u < 4; ++u) p[u] = q.x * v[u].x + q.y * v[u].y;
#pragma unroll
    for (int ofs = 32; ofs >= 1; ofs >>= 1) {
#pragma unroll
      for (int u = 0; u < 4; ++u) p[u] += __shfl_xor(p[u], ofs);
    }
#pragma unroll
    for (int u = 0; u < 4; ++u) {
      a2.x += p[u] * v[u].x; a2.y += p[u] * v[u].y;
    }
  }
  for (; e < end; ++e) {
    int j = s2[e];
    unsigned int w = *(const unsigned int*)&hb[(size_t)j * D + f];
    float2 v = make_float2(bf_lo(w), bf_hi(w));
    float p = wave_reduce_sum(q.x * v.x + q.y * v.y);
    a2.x += p * v.x; a2.y += p * v.y;
  }

  *(float2*)&G[(size_t)i * 256 + f] = a1;
  *(float2*)&G[(size_t)i * 256 + 128 + f] = a2;
}

// ---------------- LDS-free GEMM ----------------
// tile 32 rows x 64 cols, 128 threads, 4x4 microtile, A/B straight from L1/L2.
// W path (by < nby_w): B = Bw, outcol = by*64 ; Q path: B = Bm, outcol = 128+(by-nby_w)*64
__global__ __launch_bounds__(128) void gemm_k(
    const float* __restrict__ A0, int lda0,
    const float* __restrict__ A1, const float* __restrict__ A2,
    int nseg,
    const float* __restrict__ Bw, const float* __restrict__ Bm, int nby_w,
    float* __restrict__ C, int ldC,
    unsigned short* __restrict__ Hb,                // optional bf16 copy of cols 0..127
    int N) {
  const int tid = threadIdx.x;
  const int by = blockIdx.y;
  const float* __restrict__ B = (by < nby_w) ? Bw : Bm;
  const int bcol = (by < nby_w) ? by * 64 : (by - nby_w) * 64;
  const int outcol = (by < nby_w) ? by * 64 : 128 + (by - nby_w) * 64;
  const int row0 = blockIdx.x * 32;

  const int tx = tid & 15, ty = tid >> 4;     // tx: 16 col-groups, ty: 8 row-groups
  const int ry = ty * 4, cx = tx * 4;

  // clamped row indices (stores are guarded)
  int r_[4];
#pragma unroll
  for (int ii = 0; ii < 4; ++ii) {
    int r = row0 + ry + ii;
    r_[ii] = (r < N) ? r : (N - 1);
  }

  float acc[4][4] = {};

  for (int seg = 0; seg < nseg; ++seg) {
    const float* __restrict__ As = (seg == 0) ? A0 : (seg == 1) ? A1 : A2;
    const long lda = (seg == 0) ? lda0 : 256;
    const float* __restrict__ Bseg = B + seg * 128 * D;

#pragma unroll 2
    for (int kk = 0; kk < 128; kk += 4) {
      float4 b0 = *(const float4*)&Bseg[(kk + 0) * D + bcol + cx];
      float4 b1 = *(const float4*)&Bseg[(kk + 1) * D + bcol + cx];
      float4 b2 = *(const float4*)&Bseg[(kk + 2) * D + bcol + cx];
      float4 b3 = *(const float4*)&Bseg[(kk + 3) * D + bcol + cx];
      float4 a0 = *(const float4*)&As[r_[0] * lda + kk];
      float4 a1 = *(const float4*)&As[r_[1] * lda + kk];
      float4 a2 = *(const float4*)&As[r_[2] * lda + kk];
      float4 a3 = *(const float4*)&As[r_[3] * lda + kk];
#define ROWFMA(ii, av)                                                        \
      acc[ii][0] += av.x * b0.x + av.y * b1.x + av.z * b2.x + av.w * b3.x;    \
      acc[ii][1] += av.x * b0.y + av.y * b1.y + av.z * b2.y + av.w * b3.y;    \
      acc[ii][2] += av.x * b0.z + av.y * b1.z + av.z * b2.z + av.w * b3.z;    \
      acc[ii][3] += av.x * b0.w + av.y * b1.w + av.z * b2.w + av.w * b3.w;
      ROWFMA(0, a0) ROWFMA(1, a1) ROWFMA(2, a2) ROWFMA(3, a3)
#undef ROWFMA
    }
  }

#pragma unroll
  for (int ii = 0; ii < 4; ++ii) {
    int row = row0 + ry + ii;
    if (row < N) {
      float4 o = make_float4(acc[ii][0], acc[ii][1], acc[ii][2], acc[ii][3]);
      *(float4*)&C[(size_t)row * ldC + outcol + cx] = o;
      if (Hb && by < nby_w) {
        ushort4 ob;
        ob.x = f2bf(o.x); ob.y = f2bf(o.y); ob.z = f2bf(o.z); ob.w = f2bf(o.w);
        *(ushort4*)&Hb[(size_t)row * D + outcol + cx] = ob;
      }
    }
  }
}

// ---------------- host ----------------

extern "C" void kernel_launch(void* const* d_in, const int* in_sizes, int n_in,
                              void* d_out, int out_size, void* d_ws, size_t ws_size,
                              hipStream_t stream) {
  const float* x  = (const float*)d_in[0];
  const int* ei1  = (const int*)d_in[1];
  const int* ei2  = (const int*)d_in[2];
  const float* W0 = (const float*)d_in[3];
  const float* W1 = (const float*)d_in[4];
  const float* Wq = (const float*)d_in[5];
  const float* Wk = (const float*)d_in[6];
  const float* Wv = (const float*)d_in[7];

  const int N  = in_sizes[0] / D;
  const int E1 = in_sizes[1] / 2;
  const int E2 = in_sizes[2] / 2;
  const int* src1 = ei1;
  const int* dst1 = ei1 + E1;
  const int* src2 = ei2;
  const int* dst2 = ei2 + E2;

  float* H2A = (float*)d_ws;                 // N x 256  [h | Qt]
  float* H2B = H2A + (size_t)N * 256;        // N x 256
  float* G   = H2B + (size_t)N * 256;        // N x 256  [agg1 | aggA]
  float* M   = G   + (size_t)N * 256;        // 128x128
  float* Wc  = M + 128 * D;                  // 384x128
  float* WM  = Wc + 384 * D;                 // 384x128
  unsigned short* hb = (unsigned short*)(WM + 384 * D);   // N x 128 bf16
  int* rp1   = (int*)(hb + (size_t)N * D);   // N+1
  int* rp2   = rp1 + (N + 1);                // N+1
  int* cur1  = rp2 + (N + 1);                // N
  int* cur2  = cur1 + N;                     // N
  int* srcs1 = cur2 + N;                     // E1
  int* srcs2 = srcs1 + E1;                   // E2

  size_t needed = ((size_t)N * 768 + 128 * D + 2 * 384 * D) * 4ull +
                  (size_t)N * D * 2ull +
                  ((size_t)2 * (N + 1) + 2ull * N + E1 + E2) * 4ull;
  if (ws_size < needed) return;

  float* out = (float*)d_out;

  // weight precompute
  mk_M<<<128, 128, 0, stream>>>(Wq, Wk, M);
  mk_Wcat<<<(384 * D + 255) / 256, 256, 0, stream>>>(W0, W1, Wv, Wc);
  mk_WM<<<384, 128, 0, stream>>>(Wc, M, WM);

  // CSR build
  hipMemsetAsync(cur1, 0, (size_t)N * sizeof(int), stream);
  hipMemsetAsync(cur2, 0, (size_t)N * sizeof(int), stream);
  int eb1 = (E1 + 255) / 256, eb2 = (E2 + 255) / 256;
  hist_k<<<eb1, 256, 0, stream>>>(dst1, cur1, E1);
  hist_k<<<eb2, 256, 0, stream>>>(dst2, cur2, E2);
  exscan2_k<<<2, 1024, 0, stream>>>(cur1, rp1, cur2, rp2, N);
  fill_k<<<eb1, 256, 0, stream>>>(src1, dst1, cur1, srcs1, E1);
  fill_k<<<eb2, 256, 0, stream>>>(src2, dst2, cur2, srcs2, E2);

  // bf16 copy of x
  cvt_k<<<(N * D / 4 + 255) / 256, 256, 0, stream>>>(x, hb, N * D / 4);

  const int gx = (N + 31) / 32;
  const int ablocks = (N * 64 + 255) / 256;

  // Qt0 = x @ M  -> H2B cols 128..255
  gemm_k<<<dim3(gx, 2), 128, 0, stream>>>(x, D, nullptr, nullptr, 1,
                                          nullptr, M, 0, H2B, 256, nullptr, N);

  for (int s = 0; s < 5; ++s) {
    const float* hsrc;
    int ldh;
    if (s == 0)      { hsrc = x;   ldh = D; }
    else if (s & 1)  { hsrc = H2A; ldh = 256; }   // s1,s3 read H2A (written s0,s2)
    else             { hsrc = H2B; ldh = 256; }   // s2,s4 read H2B (written s1,s3)
    const float* qtsrc = (s == 0) ? (H2B + 128) : (hsrc + 128);

    agg_k<<<ablocks, 256, 0, stream>>>(hb, qtsrc, 256,
                                       rp1, srcs1, rp2, srcs2, G, N);

    if (s == 4) {
      gemm_k<<<dim3(gx, 2), 128, 0, stream>>>(hsrc, ldh, G, G + 128, 3,
                                              Wc, WM, 2, out, D, nullptr, N);
    } else {
      float* Cdst = (s & 1) ? H2B : H2A;
      gemm_k<<<dim3(gx, 4), 128, 0, stream>>>(hsrc, ldh, G, G + 128, 3,
                                              Wc, WM, 2, Cdst, 256, hb, N);
    }
  }
}

// Round 4
// 520.891 us; speedup vs baseline: 1.2524x; 1.2524x over previous
//
#include <hip/hip_runtime.h>

#define D 128

typedef __attribute__((ext_vector_type(8))) short bf16x8;
typedef __attribute__((ext_vector_type(4))) float f32x4;

// ---------------- bf16 split helpers (RTN-even) ----------------
__device__ __forceinline__ unsigned short f2bf(float f) {
  union { float f; unsigned int u; } c; c.f = f;
  unsigned int u = c.u;
  unsigned int r = (u + 0x7fffu + ((u >> 16) & 1u)) >> 16;
  return (unsigned short)r;
}
__device__ __forceinline__ float bf2f(unsigned short h) {
  return __uint_as_float(((unsigned int)h) << 16);
}
__device__ __forceinline__ void split2(float a, float b, unsigned int& hi, unsigned int& lo) {
  unsigned short ha = f2bf(a), hb = f2bf(b);
  unsigned short la = f2bf(a - bf2f(ha)), lb = f2bf(b - bf2f(hb));
  hi = (unsigned int)ha | ((unsigned int)hb << 16);
  lo = (unsigned int)la | ((unsigned int)lb << 16);
}

// ---------------- CSR build ----------------

__global__ void hist_k(const int* __restrict__ dst, int* __restrict__ cnt, int E) {
  int e = blockIdx.x * blockDim.x + threadIdx.x;
  if (e < E) atomicAdd(&cnt[dst[e]], 1);
}

__device__ void exscan_dev(int* cnt_cursor, int* rp, int n) {
  __shared__ int wsum[16];
  __shared__ int carry_s;
  const int tid = threadIdx.x;
  const int lane = tid & 63, wid = tid >> 6;
  if (tid == 0) carry_s = 0;
  __syncthreads();
  for (int base = 0; base < n; base += 1024) {
    int idx = base + tid;
    int v = (idx < n) ? cnt_cursor[idx] : 0;
    int s = v;
#pragma unroll
    for (int ofs = 1; ofs < 64; ofs <<= 1) {
      int t = __shfl_up(s, ofs);
      if (lane >= ofs) s += t;
    }
    if (lane == 63) wsum[wid] = s;
    __syncthreads();
    if (wid == 0) {
      int ws = (lane < 16) ? wsum[lane] : 0;
#pragma unroll
      for (int ofs = 1; ofs < 16; ofs <<= 1) {
        int t = __shfl_up(ws, ofs);
        if (lane >= ofs) ws += t;
      }
      if (lane < 16) wsum[lane] = ws;
    }
    __syncthreads();
    int pre = (wid > 0) ? wsum[wid - 1] : 0;
    int carry = carry_s;
    int ex = carry + pre + s - v;
    if (idx < n) { rp[idx] = ex; cnt_cursor[idx] = ex; }
    __syncthreads();
    if (tid == 1023) carry_s = carry + wsum[15];
    __syncthreads();
  }
  if (tid == 0) rp[n] = carry_s;
}

__global__ void exscan2_k(int* c1, int* r1, int* c2, int* r2, int n) {
  if (blockIdx.x == 0) exscan_dev(c1, r1, n);
  else exscan_dev(c2, r2, n);
}

__global__ void fill_k(const int* __restrict__ src, const int* __restrict__ dst,
                       int* __restrict__ cursor, int* __restrict__ srcs, int E) {
  int e = blockIdx.x * blockDim.x + threadIdx.x;
  if (e < E) {
    int pos = atomicAdd(&cursor[dst[e]], 1);
    srcs[pos] = src[e];
  }
}

// ---------------- weight precompute ----------------
__global__ __launch_bounds__(128) void mk_M(const float* __restrict__ Wq,
                                            const float* __restrict__ Wk,
                                            float* __restrict__ M) {
  int r = blockIdx.x, c = threadIdx.x;
  float acc = 0.f;
  for (int d = 0; d < D; ++d) acc += Wq[r * D + d] * Wk[c * D + d];
  M[r * D + c] = acc;
}

__global__ __launch_bounds__(256) void mk_Wcat(const float* __restrict__ W0,
                                               const float* __restrict__ W1,
                                               const float* __restrict__ Wv,
                                               float* __restrict__ Wc) {
  int idx = blockIdx.x * blockDim.x + threadIdx.x;
  if (idx >= 384 * D) return;
  int r = idx >> 7, c = idx & 127;
  float v;
  if (r < 128) v = W0[r * D + c];
  else if (r < 256) v = W1[(r - 128) * D + c];
  else v = -Wv[(r - 256) * D + c];
  Wc[idx] = v;
}

__global__ __launch_bounds__(128) void mk_WM(const float* __restrict__ Wc,
                                             const float* __restrict__ M,
                                             float* __restrict__ WM) {
  int r = blockIdx.x, c = threadIdx.x;
  float acc = 0.f;
  for (int k = 0; k < D; ++k) acc += Wc[r * D + k] * M[k * D + c];
  WM[r * D + c] = acc;
}

// Bt[n][k] = B[k][n], split hi/lo. B = [Wc | WM] (384 x 256)
__global__ __launch_bounds__(256) void mk_Bt(const float* __restrict__ Wc,
                                             const float* __restrict__ WM,
                                             unsigned short* __restrict__ Bthi,
                                             unsigned short* __restrict__ Btlo) {
  int idx = blockIdx.x * blockDim.x + threadIdx.x;
  if (idx >= 256 * 384) return;
  int n = idx / 384, k = idx - n * 384;
  float v = (n < 128) ? Wc[k * D + n] : WM[k * D + (n - 128)];
  unsigned short h = f2bf(v);
  Bthi[idx] = h;
  Btlo[idx] = f2bf(v - bf2f(h));
}

// Mt[n][k] = M[k][n], split hi/lo (128 x 128)
__global__ __launch_bounds__(256) void mk_Mt(const float* __restrict__ M,
                                             unsigned short* __restrict__ Mthi,
                                             unsigned short* __restrict__ Mtlo) {
  int idx = blockIdx.x * blockDim.x + threadIdx.x;
  if (idx >= 128 * 128) return;
  int n = idx >> 7, k = idx & 127;
  float v = M[k * D + n];
  unsigned short h = f2bf(v);
  Mthi[idx] = h;
  Mtlo[idx] = f2bf(v - bf2f(h));
}

// x -> A cols 0..127 (split bf16)
__global__ __launch_bounds__(256) void cvt_k(const float* __restrict__ x,
                                             unsigned short* __restrict__ Ahi,
                                             unsigned short* __restrict__ Alo, int n4) {
  int i = blockIdx.x * blockDim.x + threadIdx.x;
  if (i >= n4) return;
  int row = i >> 5, c = (i & 31) * 4;
  float4 v = *(const float4*)&x[row * D + c];
  unsigned int h0, l0, h1, l1;
  split2(v.x, v.y, h0, l0);
  split2(v.z, v.w, h1, l1);
  size_t o = (size_t)row * 384 + c;
  *(uint2*)&Ahi[o] = make_uint2(h0, h1);
  *(uint2*)&Alo[o] = make_uint2(l0, l1);
}

// ---------------- gather/aggregate: one wave per node (fp32 gather) ----------------
// writes A row i: cols 0..127 = split(h_i), 128..255 = split(agg1), 256..383 = split(aggA)
__device__ __forceinline__ float wave_reduce_sum(float v) {
  v += __shfl_xor(v, 32);
  v += __shfl_xor(v, 16);
  v += __shfl_xor(v, 8);
  v += __shfl_xor(v, 4);
  v += __shfl_xor(v, 2);
  v += __shfl_xor(v, 1);
  return v;
}

__global__ __launch_bounds__(256) void agg_k(
    const float* __restrict__ h, int ldh,
    const float* __restrict__ qt,                  // ld 256
    const int* __restrict__ rp1, const int* __restrict__ s1,
    const int* __restrict__ rp2, const int* __restrict__ s2,
    unsigned short* __restrict__ Ahi, unsigned short* __restrict__ Alo, int N) {
  int gw = (int)((blockIdx.x * blockDim.x + threadIdx.x) >> 6);
  if (gw >= N) return;
  const int i = __builtin_amdgcn_readfirstlane(gw);
  const int l = threadIdx.x & 63;
  const int f = 2 * l;

  float2 hi_row = *(const float2*)&h[(size_t)i * ldh + f];
  float2 q = *(const float2*)&qt[(size_t)i * 256 + f];
  float2 a1 = make_float2(0.f, 0.f);
  float2 a2 = make_float2(0.f, 0.f);

  // TAGConv neighbor sum
  int e = rp1[i], end = rp1[i + 1];
  for (; e + 8 <= end; e += 8) {
    float2 v[8];
#pragma unroll
    for (int u = 0; u < 8; ++u) {
      int j = s1[e + u];
      v[u] = *(const float2*)&h[(size_t)j * ldh + f];
    }
#pragma unroll
    for (int u = 0; u < 8; ++u) { a1.x += v[u].x; a1.y += v[u].y; }
  }
  for (; e < end; ++e) {
    int j = s1[e];
    float2 v = *(const float2*)&h[(size_t)j * ldh + f];
    a1.x += v.x; a1.y += v.y;
  }

  // attention aggregate
  e = rp2[i]; end = rp2[i + 1];
  for (; e + 4 <= end; e += 4) {
    float2 v[4]; float p[4];
#pragma unroll
    for (int u = 0; u < 4; ++u) {
      int j = s2[e + u];
      v[u] = *(const float2*)&h[(size_t)j * ldh + f];
    }
#pragma unroll
    for (int u = 0; u < 4; ++u) p[u] = q.x * v[u].x + q.y * v[u].y;
#pragma unroll
    for (int ofs = 32; ofs >= 1; ofs >>= 1) {
#pragma unroll
      for (int u = 0; u < 4; ++u) p[u] += __shfl_xor(p[u], ofs);
    }
#pragma unroll
    for (int u = 0; u < 4; ++u) {
      a2.x += p[u] * v[u].x; a2.y += p[u] * v[u].y;
    }
  }
  for (; e < end; ++e) {
    int j = s2[e];
    float2 v = *(const float2*)&h[(size_t)j * ldh + f];
    float p = wave_reduce_sum(q.x * v.x + q.y * v.y);
    a2.x += p * v.x; a2.y += p * v.y;
  }

  size_t base = (size_t)i * 384 + f;
  unsigned int hh, hl;
  split2(hi_row.x, hi_row.y, hh, hl);
  *(unsigned int*)&Ahi[base] = hh;
  *(unsigned int*)&Alo[base] = hl;
  split2(a1.x, a1.y, hh, hl);
  *(unsigned int*)&Ahi[base + 128] = hh;
  *(unsigned int*)&Alo[base + 128] = hl;
  split2(a2.x, a2.y, hh, hl);
  *(unsigned int*)&Ahi[base + 256] = hh;
  *(unsigned int*)&Alo[base + 256] = hl;
}

// ---------------- split-bf16 MFMA GEMM ----------------
// C[m][n] = sum_k A[m][k] * B[k][n],  A = Ahi+Alo [N][lda] (uses cols 0..kdim),
// Bt[n][kdim] transposed weights. Each wave: 16 rows x 64 cols (4 n-tiles).
// Block 256 = 4 waves = 64 rows; gridDim.y selects 64-col panel.
__global__ __launch_bounds__(256) void gemm_mfma(
    const unsigned short* __restrict__ Ahi, const unsigned short* __restrict__ Alo,
    int lda, int kdim,
    const unsigned short* __restrict__ Bthi, const unsigned short* __restrict__ Btlo,
    float* __restrict__ C, int ldc, int N) {
  const int w = threadIdx.x >> 6;
  const int l = threadIdx.x & 63;
  const int row_t = blockIdx.x * 64 + w * 16;
  const int col0 = blockIdx.y * 64;

  int arow = row_t + (l & 15);
  if (arow >= N) arow = N - 1;
  const int kl = 8 * (l >> 4);
  const unsigned short* ap_hi = Ahi + (size_t)arow * lda + kl;
  const unsigned short* ap_lo = Alo + (size_t)arow * lda + kl;
  const int bn = col0 + (l & 15);
  const unsigned short* bp_hi = Bthi + (size_t)bn * kdim + kl;
  const unsigned short* bp_lo = Btlo + (size_t)bn * kdim + kl;

  f32x4 acc[4] = {};
#pragma unroll 2
  for (int k0 = 0; k0 < kdim; k0 += 32) {
    bf16x8 ah = *(const bf16x8*)(ap_hi + k0);
    bf16x8 al = *(const bf16x8*)(ap_lo + k0);
#pragma unroll
    for (int nt = 0; nt < 4; ++nt) {
      bf16x8 bh = *(const bf16x8*)(bp_hi + (size_t)nt * 16 * kdim + k0);
      bf16x8 bl = *(const bf16x8*)(bp_lo + (size_t)nt * 16 * kdim + k0);
      acc[nt] = __builtin_amdgcn_mfma_f32_16x16x32_bf16(ah, bh, acc[nt], 0, 0, 0);
      acc[nt] = __builtin_amdgcn_mfma_f32_16x16x32_bf16(ah, bl, acc[nt], 0, 0, 0);
      acc[nt] = __builtin_amdgcn_mfma_f32_16x16x32_bf16(al, bh, acc[nt], 0, 0, 0);
    }
  }

  const int crow0 = row_t + 4 * (l >> 4);
  const int ccol = col0 + (l & 15);
#pragma unroll
  for (int nt = 0; nt < 4; ++nt) {
#pragma unroll
    for (int r = 0; r < 4; ++r) {
      int row = crow0 + r;
      if (row < N) C[(size_t)row * ldc + ccol + nt * 16] = acc[nt][r];
    }
  }
}

// ---------------- host ----------------

extern "C" void kernel_launch(void* const* d_in, const int* in_sizes, int n_in,
                              void* d_out, int out_size, void* d_ws, size_t ws_size,
                              hipStream_t stream) {
  const float* x  = (const float*)d_in[0];
  const int* ei1  = (const int*)d_in[1];
  const int* ei2  = (const int*)d_in[2];
  const float* W0 = (const float*)d_in[3];
  const float* W1 = (const float*)d_in[4];
  const float* Wq = (const float*)d_in[5];
  const float* Wk = (const float*)d_in[6];
  const float* Wv = (const float*)d_in[7];

  const int N  = in_sizes[0] / D;
  const int E1 = in_sizes[1] / 2;
  const int E2 = in_sizes[2] / 2;
  const int* src1 = ei1;
  const int* dst1 = ei1 + E1;
  const int* src2 = ei2;
  const int* dst2 = ei2 + E2;

  float* Cbuf = (float*)d_ws;                     // N x 256 fp32 [h | Qt]
  float* M    = Cbuf + (size_t)N * 256;           // 128x128
  float* Wc   = M + 128 * D;                      // 384x128
  float* WM   = Wc + 384 * D;                     // 384x128
  unsigned short* Bthi = (unsigned short*)(WM + 384 * D);  // 256x384
  unsigned short* Btlo = Bthi + 256 * 384;
  unsigned short* Mthi = Btlo + 256 * 384;        // 128x128
  unsigned short* Mtlo = Mthi + 128 * 128;
  unsigned short* Ahi  = Mtlo + 128 * 128;        // N x 384
  unsigned short* Alo  = Ahi + (size_t)N * 384;
  int* rp1   = (int*)(Alo + (size_t)N * 384);
  int* rp2   = rp1 + (N + 1);
  int* cur1  = rp2 + (N + 1);
  int* cur2  = cur1 + N;
  int* srcs1 = cur2 + N;
  int* srcs2 = srcs1 + E1;

  size_t needed = ((size_t)N * 256 + 128 * D + 2 * 384 * D) * 4ull +
                  ((size_t)2 * 256 * 384 + 2 * 128 * 128 + 2ull * N * 384) * 2ull +
                  ((size_t)2 * (N + 1) + 2ull * N + E1 + E2) * 4ull;
  if (ws_size < needed) return;

  float* out = (float*)d_out;

  // weight precompute
  mk_M<<<128, 128, 0, stream>>>(Wq, Wk, M);
  mk_Wcat<<<(384 * D + 255) / 256, 256, 0, stream>>>(W0, W1, Wv, Wc);
  mk_WM<<<384, 128, 0, stream>>>(Wc, M, WM);
  mk_Bt<<<(256 * 384 + 255) / 256, 256, 0, stream>>>(Wc, WM, Bthi, Btlo);
  mk_Mt<<<(128 * 128 + 255) / 256, 256, 0, stream>>>(M, Mthi, Mtlo);

  // CSR build
  hipMemsetAsync(cur1, 0, (size_t)N * sizeof(int), stream);
  hipMemsetAsync(cur2, 0, (size_t)N * sizeof(int), stream);
  int eb1 = (E1 + 255) / 256, eb2 = (E2 + 255) / 256;
  hist_k<<<eb1, 256, 0, stream>>>(dst1, cur1, E1);
  hist_k<<<eb2, 256, 0, stream>>>(dst2, cur2, E2);
  exscan2_k<<<2, 1024, 0, stream>>>(cur1, rp1, cur2, rp2, N);
  fill_k<<<eb1, 256, 0, stream>>>(src1, dst1, cur1, srcs1, E1);
  fill_k<<<eb2, 256, 0, stream>>>(src2, dst2, cur2, srcs2, E2);

  // A cols 0..127 = split(x)
  cvt_k<<<(N * 32 + 255) / 256, 256, 0, stream>>>(x, Ahi, Alo, N * 32);

  const int gx = (N + 63) / 64;
  const int ablocks = (N * 64 + 255) / 256;

  // Qt0 = x @ M -> Cbuf cols 128..255
  gemm_mfma<<<dim3(gx, 2), 256, 0, stream>>>(Ahi, Alo, 384, 128, Mthi, Mtlo,
                                             Cbuf + 128, 256, N);

  for (int s = 0; s < 5; ++s) {
    const float* hsrc = (s == 0) ? x : Cbuf;
    const int ldh = (s == 0) ? D : 256;

    agg_k<<<ablocks, 256, 0, stream>>>(hsrc, ldh, Cbuf + 128,
                                       rp1, srcs1, rp2, srcs2, Ahi, Alo, N);

    if (s == 4) {
      gemm_mfma<<<dim3(gx, 2), 256, 0, stream>>>(Ahi, Alo, 384, 384, Bthi, Btlo,
                                                 out, D, N);
    } else {
      gemm_mfma<<<dim3(gx, 4), 256, 0, stream>>>(Ahi, Alo, 384, 384, Bthi, Btlo,
                                                 Cbuf, 256, N);
    }
  }
}

// Round 5
// 427.122 us; speedup vs baseline: 1.5274x; 1.2195x over previous
//
#include <hip/hip_runtime.h>

#define D 128

typedef __attribute__((ext_vector_type(8))) short bf16x8;
typedef __attribute__((ext_vector_type(4))) float f32x4;

// ---------------- bf16 split helpers (RTN-even) ----------------
__device__ __forceinline__ unsigned short f2bf(float f) {
  union { float f; unsigned int u; } c; c.f = f;
  unsigned int u = c.u;
  unsigned int r = (u + 0x7fffu + ((u >> 16) & 1u)) >> 16;
  return (unsigned short)r;
}
__device__ __forceinline__ float bf2f(unsigned short h) {
  return __uint_as_float(((unsigned int)h) << 16);
}
__device__ __forceinline__ void split2(float a, float b, unsigned int& hi, unsigned int& lo) {
  unsigned short ha = f2bf(a), hb = f2bf(b);
  unsigned short la = f2bf(a - bf2f(ha)), lb = f2bf(b - bf2f(hb));
  hi = (unsigned int)ha | ((unsigned int)hb << 16);
  lo = (unsigned int)la | ((unsigned int)lb << 16);
}

// A-fragment layout: Af[((t*12 + s)*64 + lane16)*8 + e], lane16 = (row&15) + 16*((k&31)>>3)
__device__ __forceinline__ void frag_write(unsigned short* __restrict__ Afh,
                                           unsigned short* __restrict__ Afl,
                                           int t, int r, int k, float a, float b) {
  unsigned int hh, hl;
  split2(a, b, hh, hl);
  int s = k >> 5, ksub = (k & 31) >> 3, e = k & 7;
  size_t addr = ((size_t)(t * 12 + s) * 64 + r + 16 * ksub) * 8 + e;
  *(unsigned int*)&Afh[addr] = hh;
  *(unsigned int*)&Afl[addr] = hl;
}

// ---------------- CSR build ----------------

__global__ void hist_k(const int* __restrict__ dst, int* __restrict__ cnt, int E) {
  int e = blockIdx.x * blockDim.x + threadIdx.x;
  if (e < E) atomicAdd(&cnt[dst[e]], 1);
}

__device__ void exscan_dev(int* cnt_cursor, int* rp, int n) {
  __shared__ int wsum[16];
  __shared__ int carry_s;
  const int tid = threadIdx.x;
  const int lane = tid & 63, wid = tid >> 6;
  if (tid == 0) carry_s = 0;
  __syncthreads();
  for (int base = 0; base < n; base += 1024) {
    int idx = base + tid;
    int v = (idx < n) ? cnt_cursor[idx] : 0;
    int s = v;
#pragma unroll
    for (int ofs = 1; ofs < 64; ofs <<= 1) {
      int t = __shfl_up(s, ofs);
      if (lane >= ofs) s += t;
    }
    if (lane == 63) wsum[wid] = s;
    __syncthreads();
    if (wid == 0) {
      int ws = (lane < 16) ? wsum[lane] : 0;
#pragma unroll
      for (int ofs = 1; ofs < 16; ofs <<= 1) {
        int t = __shfl_up(ws, ofs);
        if (lane >= ofs) ws += t;
      }
      if (lane < 16) wsum[lane] = ws;
    }
    __syncthreads();
    int pre = (wid > 0) ? wsum[wid - 1] : 0;
    int carry = carry_s;
    int ex = carry + pre + s - v;
    if (idx < n) { rp[idx] = ex; cnt_cursor[idx] = ex; }
    __syncthreads();
    if (tid == 1023) carry_s = carry + wsum[15];
    __syncthreads();
  }
  if (tid == 0) rp[n] = carry_s;
}

__global__ void exscan2_k(int* c1, int* r1, int* c2, int* r2, int n) {
  if (blockIdx.x == 0) exscan_dev(c1, r1, n);
  else exscan_dev(c2, r2, n);
}

__global__ void fill_k(const int* __restrict__ src, const int* __restrict__ dst,
                       int* __restrict__ cursor, int* __restrict__ srcs, int E) {
  int e = blockIdx.x * blockDim.x + threadIdx.x;
  if (e < E) {
    int pos = atomicAdd(&cursor[dst[e]], 1);
    srcs[pos] = src[e];
  }
}

// ---------------- weight precompute ----------------
// pre1: M = Wq Wk^T (64 blocks) ; Wc = [W0;W1;-Wv] (192 blocks)
__global__ __launch_bounds__(256) void pre1_k(
    const float* __restrict__ Wq, const float* __restrict__ Wk,
    const float* __restrict__ W0, const float* __restrict__ W1,
    const float* __restrict__ Wv,
    float* __restrict__ M, float* __restrict__ Wc) {
  int bx = blockIdx.x;
  if (bx < 64) {
    int r = bx * 2 + (threadIdx.x >> 7);
    int c = threadIdx.x & 127;
    float acc = 0.f;
    for (int d = 0; d < D; ++d) acc += Wq[r * D + d] * Wk[c * D + d];
    M[r * D + c] = acc;
  } else {
    int idx = (bx - 64) * 256 + threadIdx.x;   // < 49152
    int r = idx >> 7, c = idx & 127;
    float v;
    if (r < 128) v = W0[r * D + c];
    else if (r < 256) v = W1[(r - 128) * D + c];
    else v = -Wv[(r - 256) * D + c];
    Wc[idx] = v;
  }
}

// pre2: WM = Wc @ M (384 x 128)
__global__ __launch_bounds__(256) void pre2_k(const float* __restrict__ Wc,
                                              const float* __restrict__ M,
                                              float* __restrict__ WM) {
  int idx = blockIdx.x * blockDim.x + threadIdx.x;
  if (idx >= 384 * D) return;
  int r = idx >> 7, c = idx & 127;
  float acc = 0.f;
  for (int k = 0; k < D; ++k) acc += Wc[r * D + k] * M[k * D + c];
  WM[idx] = acc;
}

// pre3: B fragments. Bf: [ntg 16][s 12][64][8] from [Wc|WM]; Mf: [ntg 8][s 4][64][8] from M.
__global__ __launch_bounds__(256) void pre3_k(
    const float* __restrict__ Wc, const float* __restrict__ WM,
    const float* __restrict__ M,
    unsigned short* __restrict__ Bfh, unsigned short* __restrict__ Bfl,
    unsigned short* __restrict__ Mfh, unsigned short* __restrict__ Mfl) {
  int idx = blockIdx.x * blockDim.x + threadIdx.x;
  if (idx < 16 * 12 * 512) {
    int e = idx & 7, l = (idx >> 3) & 63;
    int s = (idx >> 9) % 12, ntg = idx / (12 * 512);
    int n = ntg * 16 + (l & 15);
    int k = s * 32 + (l >> 4) * 8 + e;
    float v = (n < 128) ? Wc[k * D + n] : WM[k * D + (n - 128)];
    unsigned short h = f2bf(v);
    Bfh[idx] = h;
    Bfl[idx] = f2bf(v - bf2f(h));
  } else {
    int i2 = idx - 16 * 12 * 512;
    if (i2 >= 8 * 4 * 512) return;
    int e = i2 & 7, l = (i2 >> 3) & 63;
    int s = (i2 >> 9) & 3, ntg = i2 / (4 * 512);
    int n = ntg * 16 + (l & 15);
    int k = s * 32 + (l >> 4) * 8 + e;
    float v = M[k * D + n];
    unsigned short h = f2bf(v);
    Mfh[i2] = h;
    Mfl[i2] = f2bf(v - bf2f(h));
  }
}

// x -> A fragments, steps 0..3 (cols 0..127)
__global__ __launch_bounds__(256) void cvt_k(const float* __restrict__ x,
                                             unsigned short* __restrict__ Afh,
                                             unsigned short* __restrict__ Afl, int n) {
  int idx = blockIdx.x * blockDim.x + threadIdx.x;   // n = N*64
  if (idx >= n) return;
  int row = idx >> 6, f = (idx & 63) * 2;
  float2 v = *(const float2*)&x[row * D + f];
  frag_write(Afh, Afl, row >> 4, row & 15, f, v.x, v.y);
}

// ---------------- gather/aggregate: one wave per node ----------------
__device__ __forceinline__ float wave_reduce_sum(float v) {
  v += __shfl_xor(v, 32);
  v += __shfl_xor(v, 16);
  v += __shfl_xor(v, 8);
  v += __shfl_xor(v, 4);
  v += __shfl_xor(v, 2);
  v += __shfl_xor(v, 1);
  return v;
}

__global__ __launch_bounds__(256) void agg_k(
    const float* __restrict__ h, int ldh,
    const float* __restrict__ qt,                  // ld 256
    const int* __restrict__ rp1, const int* __restrict__ s1,
    const int* __restrict__ rp2, const int* __restrict__ s2,
    unsigned short* __restrict__ Afh, unsigned short* __restrict__ Afl, int N) {
  int gw = (int)((blockIdx.x * blockDim.x + threadIdx.x) >> 6);
  if (gw >= N) return;
  const int i = __builtin_amdgcn_readfirstlane(gw);
  const int l = threadIdx.x & 63;
  const int f = 2 * l;

  float2 hrow = *(const float2*)&h[(size_t)i * ldh + f];
  float2 q = *(const float2*)&qt[(size_t)i * 256 + f];
  float2 a1 = make_float2(0.f, 0.f);
  float2 a2 = make_float2(0.f, 0.f);

  int e = rp1[i], end = rp1[i + 1];
  for (; e + 8 <= end; e += 8) {
    float2 v[8];
#pragma unroll
    for (int u = 0; u < 8; ++u) {
      int j = s1[e + u];
      v[u] = *(const float2*)&h[(size_t)j * ldh + f];
    }
#pragma unroll
    for (int u = 0; u < 8; ++u) { a1.x += v[u].x; a1.y += v[u].y; }
  }
  for (; e < end; ++e) {
    int j = s1[e];
    float2 v = *(const float2*)&h[(size_t)j * ldh + f];
    a1.x += v.x; a1.y += v.y;
  }

  e = rp2[i]; end = rp2[i + 1];
  for (; e + 4 <= end; e += 4) {
    float2 v[4]; float p[4];
#pragma unroll
    for (int u = 0; u < 4; ++u) {
      int j = s2[e + u];
      v[u] = *(const float2*)&h[(size_t)j * ldh + f];
    }
#pragma unroll
    for (int u = 0; u < 4; ++u) p[u] = q.x * v[u].x + q.y * v[u].y;
#pragma unroll
    for (int ofs = 32; ofs >= 1; ofs >>= 1) {
#pragma unroll
      for (int u = 0; u < 4; ++u) p[u] += __shfl_xor(p[u], ofs);
    }
#pragma unroll
    for (int u = 0; u < 4; ++u) {
      a2.x += p[u] * v[u].x; a2.y += p[u] * v[u].y;
    }
  }
  for (; e < end; ++e) {
    int j = s2[e];
    float2 v = *(const float2*)&h[(size_t)j * ldh + f];
    float p = wave_reduce_sum(q.x * v.x + q.y * v.y);
    a2.x += p * v.x; a2.y += p * v.y;
  }

  const int t = i >> 4, r = i & 15;
  frag_write(Afh, Afl, t, r, f, hrow.x, hrow.y);
  frag_write(Afh, Afl, t, r, 128 + f, a1.x, a1.y);
  frag_write(Afh, Afl, t, r, 256 + f, a2.x, a2.y);
}

// ---------------- fragment-layout split-bf16 MFMA GEMM ----------------
// Block 256 = 4 waves (2 row x 2 col). Wave: 32 rows (2 tiles) x 64 cols (4 n-tiles).
// A frag: [tile][12 steps][64][8] (always 12-step stride). B frag: [ntg][ksteps][64][8].
__global__ __launch_bounds__(256) void gemm_mfma(
    const unsigned short* __restrict__ Afh, const unsigned short* __restrict__ Afl,
    int ksteps,
    const unsigned short* __restrict__ Bfh, const unsigned short* __restrict__ Bfl,
    int outcol0, float* __restrict__ C, int ldc, int N, int ntiles) {
  const int w = threadIdx.x >> 6, l = threadIdx.x & 63;
  const int wr = w & 1, wc = w >> 1;
  const int rowbase = blockIdx.x * 64 + wr * 32;
  const int pc = blockIdx.y * 2 + wc;        // 64-col panel index
  int t0 = rowbase >> 4, t1 = t0 + 1;
  if (t0 > ntiles - 1) t0 = ntiles - 1;
  if (t1 > ntiles - 1) t1 = ntiles - 1;

  const size_t loff = (size_t)l * 8;
  const unsigned short* a0h = Afh + (size_t)t0 * 12 * 512 + loff;
  const unsigned short* a0l = Afl + (size_t)t0 * 12 * 512 + loff;
  const unsigned short* a1h = Afh + (size_t)t1 * 12 * 512 + loff;
  const unsigned short* a1l = Afl + (size_t)t1 * 12 * 512 + loff;
  const unsigned short* bh0 = Bfh + (size_t)pc * 4 * ksteps * 512 + loff;
  const unsigned short* bl0 = Bfl + (size_t)pc * 4 * ksteps * 512 + loff;

  f32x4 acc[2][4] = {};
  for (int s = 0; s < ksteps; ++s) {
    bf16x8 A0h = *(const bf16x8*)(a0h + (size_t)s * 512);
    bf16x8 A0l = *(const bf16x8*)(a0l + (size_t)s * 512);
    bf16x8 A1h = *(const bf16x8*)(a1h + (size_t)s * 512);
    bf16x8 A1l = *(const bf16x8*)(a1l + (size_t)s * 512);
#pragma unroll
    for (int nt = 0; nt < 4; ++nt) {
      bf16x8 Bh = *(const bf16x8*)(bh0 + ((size_t)nt * ksteps + s) * 512);
      bf16x8 Bl = *(const bf16x8*)(bl0 + ((size_t)nt * ksteps + s) * 512);
      acc[0][nt] = __builtin_amdgcn_mfma_f32_16x16x32_bf16(A0h, Bh, acc[0][nt], 0, 0, 0);
      acc[0][nt] = __builtin_amdgcn_mfma_f32_16x16x32_bf16(A0h, Bl, acc[0][nt], 0, 0, 0);
      acc[0][nt] = __builtin_amdgcn_mfma_f32_16x16x32_bf16(A0l, Bh, acc[0][nt], 0, 0, 0);
      acc[1][nt] = __builtin_amdgcn_mfma_f32_16x16x32_bf16(A1h, Bh, acc[1][nt], 0, 0, 0);
      acc[1][nt] = __builtin_amdgcn_mfma_f32_16x16x32_bf16(A1h, Bl, acc[1][nt], 0, 0, 0);
      acc[1][nt] = __builtin_amdgcn_mfma_f32_16x16x32_bf16(A1l, Bh, acc[1][nt], 0, 0, 0);
    }
  }

  const int r4 = 4 * (l >> 4), cc = (l & 15);
#pragma unroll
  for (int tr = 0; tr < 2; ++tr) {
#pragma unroll
    for (int nt = 0; nt < 4; ++nt) {
#pragma unroll
      for (int rr = 0; rr < 4; ++rr) {
        int row = rowbase + tr * 16 + r4 + rr;
        if (row < N) C[(size_t)row * ldc + outcol0 + pc * 64 + nt * 16 + cc] = acc[tr][nt][rr];
      }
    }
  }
}

// ---------------- host ----------------

extern "C" void kernel_launch(void* const* d_in, const int* in_sizes, int n_in,
                              void* d_out, int out_size, void* d_ws, size_t ws_size,
                              hipStream_t stream) {
  const float* x  = (const float*)d_in[0];
  const int* ei1  = (const int*)d_in[1];
  const int* ei2  = (const int*)d_in[2];
  const float* W0 = (const float*)d_in[3];
  const float* W1 = (const float*)d_in[4];
  const float* Wq = (const float*)d_in[5];
  const float* Wk = (const float*)d_in[6];
  const float* Wv = (const float*)d_in[7];

  const int N  = in_sizes[0] / D;
  const int E1 = in_sizes[1] / 2;
  const int E2 = in_sizes[2] / 2;
  const int* src1 = ei1;
  const int* dst1 = ei1 + E1;
  const int* src2 = ei2;
  const int* dst2 = ei2 + E2;
  const int TILES = (N + 15) / 16;

  float* Cbuf = (float*)d_ws;                       // N x 256
  float* M    = Cbuf + (size_t)N * 256;             // 128x128
  float* Wc   = M + 16384;                          // 384x128
  float* WM   = Wc + 49152;                         // 384x128
  unsigned short* Afh = (unsigned short*)(WM + 49152);   // TILES*12*512
  unsigned short* Afl = Afh + (size_t)TILES * 6144;
  unsigned short* Bfh = Afl + (size_t)TILES * 6144;      // 16*12*512
  unsigned short* Bfl = Bfh + 98304;
  unsigned short* Mfh = Bfl + 98304;                     // 8*4*512
  unsigned short* Mfl = Mfh + 16384;
  int* rp1   = (int*)(Mfl + 16384);
  int* rp2   = rp1 + (N + 1);
  int* cur1  = rp2 + (N + 1);
  int* cur2  = cur1 + N;
  int* srcs1 = cur2 + N;
  int* srcs2 = srcs1 + E1;

  size_t needed = ((size_t)N * 256 + 16384 + 2 * 49152) * 4ull +
                  ((size_t)2 * TILES * 6144 + 2 * 98304 + 2 * 16384) * 2ull +
                  ((size_t)2 * (N + 1) + 2ull * N + E1 + E2) * 4ull;
  if (ws_size < needed) return;

  float* out = (float*)d_out;

  // weight precompute (3 kernels)
  pre1_k<<<256, 256, 0, stream>>>(Wq, Wk, W0, W1, Wv, M, Wc);
  pre2_k<<<(384 * D + 255) / 256, 256, 0, stream>>>(Wc, M, WM);
  pre3_k<<<(16 * 12 * 512 + 8 * 4 * 512 + 255) / 256, 256, 0, stream>>>(
      Wc, WM, M, Bfh, Bfl, Mfh, Mfl);

  // CSR build
  hipMemsetAsync(cur1, 0, (size_t)N * sizeof(int), stream);
  hipMemsetAsync(cur2, 0, (size_t)N * sizeof(int), stream);
  int eb1 = (E1 + 255) / 256, eb2 = (E2 + 255) / 256;
  hist_k<<<eb1, 256, 0, stream>>>(dst1, cur1, E1);
  hist_k<<<eb2, 256, 0, stream>>>(dst2, cur2, E2);
  exscan2_k<<<2, 1024, 0, stream>>>(cur1, rp1, cur2, rp2, N);
  fill_k<<<eb1, 256, 0, stream>>>(src1, dst1, cur1, srcs1, E1);
  fill_k<<<eb2, 256, 0, stream>>>(src2, dst2, cur2, srcs2, E2);

  // A fragments cols 0..127 = split(x)
  cvt_k<<<(N * 64 + 255) / 256, 256, 0, stream>>>(x, Afh, Afl, N * 64);

  const int gx = (N + 63) / 64;
  const int ablocks = (N * 64 + 255) / 256;

  // Qt0 = x @ M -> Cbuf cols 128..255 (A steps 0..3, B = Mfrag)
  gemm_mfma<<<dim3(gx, 1), 256, 0, stream>>>(Afh, Afl, 4, Mfh, Mfl,
                                             128, Cbuf, 256, N, TILES);

  for (int s = 0; s < 5; ++s) {
    const float* hsrc = (s == 0) ? x : Cbuf;
    const int ldh = (s == 0) ? D : 256;

    agg_k<<<ablocks, 256, 0, stream>>>(hsrc, ldh, Cbuf + 128,
                                       rp1, srcs1, rp2, srcs2, Afh, Afl, N);

    if (s == 4) {
      gemm_mfma<<<dim3(gx, 1), 256, 0, stream>>>(Afh, Afl, 12, Bfh, Bfl,
                                                 0, out, D, N, TILES);
    } else {
      gemm_mfma<<<dim3(gx, 2), 256, 0, stream>>>(Afh, Afl, 12, Bfh, Bfl,
                                                 0, Cbuf, 256, N, TILES);
    }
  }
}

// Round 6
// 423.470 us; speedup vs baseline: 1.5406x; 1.0086x over previous
//
#include <hip/hip_runtime.h>

#define D 128

typedef __attribute__((ext_vector_type(8))) short bf16x8;
typedef __attribute__((ext_vector_type(4))) float f32x4;

// ---------------- bf16 helpers (RTN-even) ----------------
__device__ __forceinline__ unsigned short f2bf(float f) {
  union { float f; unsigned int u; } c; c.f = f;
  unsigned int u = c.u;
  unsigned int r = (u + 0x7fffu + ((u >> 16) & 1u)) >> 16;
  return (unsigned short)r;
}
__device__ __forceinline__ float bf2f(unsigned short h) {
  return __uint_as_float(((unsigned int)h) << 16);
}
__device__ __forceinline__ float bf_lo(unsigned int w) {
  return __uint_as_float(w << 16);
}
__device__ __forceinline__ float bf_hi(unsigned int w) {
  return __uint_as_float(w & 0xffff0000u);
}
__device__ __forceinline__ void split2(float a, float b, unsigned int& hi, unsigned int& lo) {
  unsigned short ha = f2bf(a), hb = f2bf(b);
  unsigned short la = f2bf(a - bf2f(ha)), lb = f2bf(b - bf2f(hb));
  hi = (unsigned int)ha | ((unsigned int)hb << 16);
  lo = (unsigned int)la | ((unsigned int)lb << 16);
}

// A-fragment layout: Af[((t*12 + s)*64 + (row&15) + 16*((k&31)>>3))*8 + (k&7)]
__device__ __forceinline__ void frag_write(unsigned short* __restrict__ Afh,
                                           unsigned short* __restrict__ Afl,
                                           int t, int r, int k, float a, float b) {
  unsigned int hh, hl;
  split2(a, b, hh, hl);
  int s = k >> 5, ksub = (k & 31) >> 3, e = k & 7;
  size_t addr = ((size_t)(t * 12 + s) * 64 + r + 16 * ksub) * 8 + e;
  *(unsigned int*)&Afh[addr] = hh;
  *(unsigned int*)&Afl[addr] = hl;
}

// ---------------- CSR build ----------------

__global__ void hist2_k(const int* __restrict__ dst1, int* __restrict__ c1, int E1,
                        const int* __restrict__ dst2, int* __restrict__ c2, int E2) {
  int e = blockIdx.x * blockDim.x + threadIdx.x;
  if (e < E1) atomicAdd(&c1[dst1[e]], 1);
  int e2 = e - E1;
  if (e2 >= 0 && e2 < E2) atomicAdd(&c2[dst2[e2]], 1);
}

__device__ void exscan_dev(int* cnt_cursor, int* rp, int n) {
  __shared__ int wsum[16];
  __shared__ int carry_s;
  const int tid = threadIdx.x;
  const int lane = tid & 63, wid = tid >> 6;
  if (tid == 0) carry_s = 0;
  __syncthreads();
  for (int base = 0; base < n; base += 1024) {
    int idx = base + tid;
    int v = (idx < n) ? cnt_cursor[idx] : 0;
    int s = v;
#pragma unroll
    for (int ofs = 1; ofs < 64; ofs <<= 1) {
      int t = __shfl_up(s, ofs);
      if (lane >= ofs) s += t;
    }
    if (lane == 63) wsum[wid] = s;
    __syncthreads();
    if (wid == 0) {
      int ws = (lane < 16) ? wsum[lane] : 0;
#pragma unroll
      for (int ofs = 1; ofs < 16; ofs <<= 1) {
        int t = __shfl_up(ws, ofs);
        if (lane >= ofs) ws += t;
      }
      if (lane < 16) wsum[lane] = ws;
    }
    __syncthreads();
    int pre = (wid > 0) ? wsum[wid - 1] : 0;
    int carry = carry_s;
    int ex = carry + pre + s - v;
    if (idx < n) { rp[idx] = ex; cnt_cursor[idx] = ex; }
    __syncthreads();
    if (tid == 1023) carry_s = carry + wsum[15];
    __syncthreads();
  }
  if (tid == 0) rp[n] = carry_s;
}

__global__ void exscan2_k(int* c1, int* r1, int* c2, int* r2, int n) {
  if (blockIdx.x == 0) exscan_dev(c1, r1, n);
  else exscan_dev(c2, r2, n);
}

__global__ void fill2_k(const int* __restrict__ src1, const int* __restrict__ dst1,
                        int* __restrict__ cur1, int* __restrict__ out1, int E1,
                        const int* __restrict__ src2, const int* __restrict__ dst2,
                        int* __restrict__ cur2, int* __restrict__ out2, int E2) {
  int e = blockIdx.x * blockDim.x + threadIdx.x;
  if (e < E1) {
    int pos = atomicAdd(&cur1[dst1[e]], 1);
    out1[pos] = src1[e];
  }
  int e2 = e - E1;
  if (e2 >= 0 && e2 < E2) {
    int pos = atomicAdd(&cur2[dst2[e2]], 1);
    out2[pos] = src2[e2];
  }
}

// ---------------- weight precompute ----------------
__global__ __launch_bounds__(256) void pre1_k(
    const float* __restrict__ Wq, const float* __restrict__ Wk,
    const float* __restrict__ W0, const float* __restrict__ W1,
    const float* __restrict__ Wv,
    float* __restrict__ M, float* __restrict__ Wc) {
  int bx = blockIdx.x;
  if (bx < 64) {
    int r = bx * 2 + (threadIdx.x >> 7);
    int c = threadIdx.x & 127;
    float acc = 0.f;
    for (int d = 0; d < D; ++d) acc += Wq[r * D + d] * Wk[c * D + d];
    M[r * D + c] = acc;
  } else {
    int idx = (bx - 64) * 256 + threadIdx.x;
    int r = idx >> 7, c = idx & 127;
    float v;
    if (r < 128) v = W0[r * D + c];
    else if (r < 256) v = W1[(r - 128) * D + c];
    else v = -Wv[(r - 256) * D + c];
    Wc[idx] = v;
  }
}

__global__ __launch_bounds__(256) void pre2_k(const float* __restrict__ Wc,
                                              const float* __restrict__ M,
                                              float* __restrict__ WM) {
  int idx = blockIdx.x * blockDim.x + threadIdx.x;
  if (idx >= 384 * D) return;
  int r = idx >> 7, c = idx & 127;
  float acc = 0.f;
  for (int k = 0; k < D; ++k) acc += Wc[r * D + k] * M[k * D + c];
  WM[idx] = acc;
}

// pre3: B fragments. Bf: [ntg 16][s 12][64][8] from [Wc|WM]; Mf: [ntg 8][s 4][64][8] from M.
__global__ __launch_bounds__(256) void pre3_k(
    const float* __restrict__ Wc, const float* __restrict__ WM,
    const float* __restrict__ M,
    unsigned short* __restrict__ Bfh, unsigned short* __restrict__ Bfl,
    unsigned short* __restrict__ Mfh, unsigned short* __restrict__ Mfl) {
  int idx = blockIdx.x * blockDim.x + threadIdx.x;
  if (idx < 16 * 12 * 512) {
    int e = idx & 7, l = (idx >> 3) & 63;
    int s = (idx >> 9) % 12, ntg = idx / (12 * 512);
    int n = ntg * 16 + (l & 15);
    int k = s * 32 + (l >> 4) * 8 + e;
    float v = (n < 128) ? Wc[k * D + n] : WM[k * D + (n - 128)];
    unsigned short h = f2bf(v);
    Bfh[idx] = h;
    Bfl[idx] = f2bf(v - bf2f(h));
  } else {
    int i2 = idx - 16 * 12 * 512;
    if (i2 >= 8 * 4 * 512) return;
    int e = i2 & 7, l = (i2 >> 3) & 63;
    int s = (i2 >> 9) & 3, ntg = i2 / (4 * 512);
    int n = ntg * 16 + (l & 15);
    int k = s * 32 + (l >> 4) * 8 + e;
    float v = M[k * D + n];
    unsigned short h = f2bf(v);
    Mfh[i2] = h;
    Mfl[i2] = f2bf(v - bf2f(h));
  }
}

// x -> A fragments cols 0..127 AND compact bf16 copy Hb
__global__ __launch_bounds__(256) void cvt_k(const float* __restrict__ x,
                                             unsigned short* __restrict__ Afh,
                                             unsigned short* __restrict__ Afl,
                                             unsigned short* __restrict__ Hb, int n) {
  int idx = blockIdx.x * blockDim.x + threadIdx.x;   // n = N*64
  if (idx >= n) return;
  int row = idx >> 6, f = (idx & 63) * 2;
  float2 v = *(const float2*)&x[row * D + f];
  frag_write(Afh, Afl, row >> 4, row & 15, f, v.x, v.y);
  unsigned int p = (unsigned int)f2bf(v.x) | ((unsigned int)f2bf(v.y) << 16);
  *(unsigned int*)&Hb[(size_t)row * D + f] = p;
}

// ---------------- gather/aggregate: one wave per node, bf16 L2-resident gather ----------------
__device__ __forceinline__ float wave_reduce_sum(float v) {
  v += __shfl_xor(v, 32);
  v += __shfl_xor(v, 16);
  v += __shfl_xor(v, 8);
  v += __shfl_xor(v, 4);
  v += __shfl_xor(v, 2);
  v += __shfl_xor(v, 1);
  return v;
}

__global__ __launch_bounds__(256) void agg_k(
    const float* __restrict__ h, int ldh,
    const float* __restrict__ qt,                  // ld 256
    const unsigned short* __restrict__ Hb,         // N x 128 bf16 (gather source)
    const int* __restrict__ rp1, const int* __restrict__ s1,
    const int* __restrict__ rp2, const int* __restrict__ s2,
    unsigned short* __restrict__ Afh, unsigned short* __restrict__ Afl, int N) {
  int gw = (int)((blockIdx.x * blockDim.x + threadIdx.x) >> 6);
  if (gw >= N) return;
  const int i = __builtin_amdgcn_readfirstlane(gw);
  const int l = threadIdx.x & 63;
  const int f = 2 * l;

  float2 hrow = *(const float2*)&h[(size_t)i * ldh + f];
  float2 q = *(const float2*)&qt[(size_t)i * 256 + f];
  float2 a1 = make_float2(0.f, 0.f);
  float2 a2 = make_float2(0.f, 0.f);

  int e = rp1[i], end = rp1[i + 1];
  for (; e + 8 <= end; e += 8) {
    unsigned int w[8];
#pragma unroll
    for (int u = 0; u < 8; ++u) {
      int j = s1[e + u];
      w[u] = *(const unsigned int*)&Hb[(size_t)j * D + f];
    }
#pragma unroll
    for (int u = 0; u < 8; ++u) { a1.x += bf_lo(w[u]); a1.y += bf_hi(w[u]); }
  }
  for (; e < end; ++e) {
    int j = s1[e];
    unsigned int w = *(const unsigned int*)&Hb[(size_t)j * D + f];
    a1.x += bf_lo(w); a1.y += bf_hi(w);
  }

  e = rp2[i]; end = rp2[i + 1];
  for (; e + 4 <= end; e += 4) {
    float2 v[4]; float p[4];
#pragma unroll
    for (int u = 0; u < 4; ++u) {
      int j = s2[e + u];
      unsigned int w = *(const unsigned int*)&Hb[(size_t)j * D + f];
      v[u] = make_float2(bf_lo(w), bf_hi(w));
    }
#pragma unroll
    for (int u = 0; u < 4; ++u) p[u] = q.x * v[u].x + q.y * v[u].y;
#pragma unroll
    for (int ofs = 32; ofs >= 1; ofs >>= 1) {
#pragma unroll
      for (int u = 0; u < 4; ++u) p[u] += __shfl_xor(p[u], ofs);
    }
#pragma unroll
    for (int u = 0; u < 4; ++u) {
      a2.x += p[u] * v[u].x; a2.y += p[u] * v[u].y;
    }
  }
  for (; e < end; ++e) {
    int j = s2[e];
    unsigned int w = *(const unsigned int*)&Hb[(size_t)j * D + f];
    float2 v = make_float2(bf_lo(w), bf_hi(w));
    float p = wave_reduce_sum(q.x * v.x + q.y * v.y);
    a2.x += p * v.x; a2.y += p * v.y;
  }

  const int t = i >> 4, r = i & 15;
  frag_write(Afh, Afl, t, r, f, hrow.x, hrow.y);
  frag_write(Afh, Afl, t, r, 128 + f, a1.x, a1.y);
  frag_write(Afh, Afl, t, r, 256 + f, a2.x, a2.y);
}

// ---------------- fragment-layout split-bf16 MFMA GEMM ----------------
// Block 256 = 4 waves (2 row-halves x 2 col-halves). Wave: 64 rows (4 tiles) x 64 cols (4 ntiles).
// Block covers 128 rows x 128 cols. 48 MFMA : 16 loads per k-step.
__global__ __launch_bounds__(256) void gemm_mfma(
    const unsigned short* __restrict__ Afh, const unsigned short* __restrict__ Afl,
    int ksteps,
    const unsigned short* __restrict__ Bfh, const unsigned short* __restrict__ Bfl,
    int outcol0, float* __restrict__ C, int ldc,
    unsigned short* __restrict__ Hb,            // optional bf16 copy (main gemm, cols<128)
    int N, int ntiles) {
  const int w = threadIdx.x >> 6, l = threadIdx.x & 63;
  const int wr = w & 1, wc = w >> 1;
  const int rowbase = blockIdx.x * 128 + wr * 64;
  const int pc = blockIdx.y * 2 + wc;          // 64-col panel index

  int t_[4];
#pragma unroll
  for (int tr = 0; tr < 4; ++tr) {
    int t = (rowbase >> 4) + tr;
    t_[tr] = (t < ntiles) ? t : (ntiles - 1);
  }

  const size_t loff = (size_t)l * 8;
  const unsigned short* ah[4];
  const unsigned short* al[4];
#pragma unroll
  for (int tr = 0; tr < 4; ++tr) {
    ah[tr] = Afh + (size_t)t_[tr] * 12 * 512 + loff;
    al[tr] = Afl + (size_t)t_[tr] * 12 * 512 + loff;
  }
  const unsigned short* bh0 = Bfh + (size_t)pc * 4 * ksteps * 512 + loff;
  const unsigned short* bl0 = Bfl + (size_t)pc * 4 * ksteps * 512 + loff;

  f32x4 acc[4][4] = {};
  for (int s = 0; s < ksteps; ++s) {
    bf16x8 Ah[4], Al[4];
#pragma unroll
    for (int tr = 0; tr < 4; ++tr) {
      Ah[tr] = *(const bf16x8*)(ah[tr] + (size_t)s * 512);
      Al[tr] = *(const bf16x8*)(al[tr] + (size_t)s * 512);
    }
#pragma unroll
    for (int nt = 0; nt < 4; ++nt) {
      bf16x8 Bh = *(const bf16x8*)(bh0 + ((size_t)nt * ksteps + s) * 512);
      bf16x8 Bl = *(const bf16x8*)(bl0 + ((size_t)nt * ksteps + s) * 512);
#pragma unroll
      for (int tr = 0; tr < 4; ++tr) {
        acc[tr][nt] = __builtin_amdgcn_mfma_f32_16x16x32_bf16(Ah[tr], Bh, acc[tr][nt], 0, 0, 0);
        acc[tr][nt] = __builtin_amdgcn_mfma_f32_16x16x32_bf16(Ah[tr], Bl, acc[tr][nt], 0, 0, 0);
        acc[tr][nt] = __builtin_amdgcn_mfma_f32_16x16x32_bf16(Al[tr], Bh, acc[tr][nt], 0, 0, 0);
      }
    }
  }

  const int r4 = 4 * (l >> 4), cc = (l & 15);
  const int colp = outcol0 + pc * 64;
#pragma unroll
  for (int tr = 0; tr < 4; ++tr) {
#pragma unroll
    for (int nt = 0; nt < 4; ++nt) {
#pragma unroll
      for (int rr = 0; rr < 4; ++rr) {
        int row = rowbase + tr * 16 + r4 + rr;
        if (row < N) {
          int col = colp + nt * 16 + cc;
          float v = acc[tr][nt][rr];
          C[(size_t)row * ldc + col] = v;
          if (Hb && col < 128) Hb[(size_t)row * D + col] = f2bf(v);
        }
      }
    }
  }
}

// ---------------- host ----------------

extern "C" void kernel_launch(void* const* d_in, const int* in_sizes, int n_in,
                              void* d_out, int out_size, void* d_ws, size_t ws_size,
                              hipStream_t stream) {
  const float* x  = (const float*)d_in[0];
  const int* ei1  = (const int*)d_in[1];
  const int* ei2  = (const int*)d_in[2];
  const float* W0 = (const float*)d_in[3];
  const float* W1 = (const float*)d_in[4];
  const float* Wq = (const float*)d_in[5];
  const float* Wk = (const float*)d_in[6];
  const float* Wv = (const float*)d_in[7];

  const int N  = in_sizes[0] / D;
  const int E1 = in_sizes[1] / 2;
  const int E2 = in_sizes[2] / 2;
  const int* src1 = ei1;
  const int* dst1 = ei1 + E1;
  const int* src2 = ei2;
  const int* dst2 = ei2 + E2;
  const int TILES = (N + 15) / 16;

  float* Cbuf = (float*)d_ws;                       // N x 256
  float* M    = Cbuf + (size_t)N * 256;             // 128x128
  float* Wc   = M + 16384;                          // 384x128
  float* WM   = Wc + 49152;                         // 384x128
  unsigned short* Afh = (unsigned short*)(WM + 49152);   // TILES*12*512
  unsigned short* Afl = Afh + (size_t)TILES * 6144;
  unsigned short* Bfh = Afl + (size_t)TILES * 6144;      // 16*12*512
  unsigned short* Bfl = Bfh + 98304;
  unsigned short* Mfh = Bfl + 98304;                     // 8*4*512
  unsigned short* Mfl = Mfh + 16384;
  unsigned short* Hb  = Mfl + 16384;                     // N x 128 bf16
  int* rp1   = (int*)(Hb + (size_t)N * D);
  int* rp2   = rp1 + (N + 1);
  int* cur1  = rp2 + (N + 1);
  int* cur2  = cur1 + N;
  int* srcs1 = cur2 + N;
  int* srcs2 = srcs1 + E1;

  size_t needed = ((size_t)N * 256 + 16384 + 2 * 49152) * 4ull +
                  ((size_t)2 * TILES * 6144 + 2 * 98304 + 2 * 16384 + (size_t)N * D) * 2ull +
                  ((size_t)2 * (N + 1) + 2ull * N + E1 + E2) * 4ull;
  if (ws_size < needed) return;

  float* out = (float*)d_out;

  // weight precompute
  pre1_k<<<256, 256, 0, stream>>>(Wq, Wk, W0, W1, Wv, M, Wc);
  pre2_k<<<(384 * D + 255) / 256, 256, 0, stream>>>(Wc, M, WM);
  pre3_k<<<(16 * 12 * 512 + 8 * 4 * 512 + 255) / 256, 256, 0, stream>>>(
      Wc, WM, M, Bfh, Bfl, Mfh, Mfl);

  // CSR build
  hipMemsetAsync(cur1, 0, (size_t)N * sizeof(int), stream);
  hipMemsetAsync(cur2, 0, (size_t)N * sizeof(int), stream);
  int ebt = (E1 + E2 + 255) / 256;
  hist2_k<<<ebt, 256, 0, stream>>>(dst1, cur1, E1, dst2, cur2, E2);
  exscan2_k<<<2, 1024, 0, stream>>>(cur1, rp1, cur2, rp2, N);
  fill2_k<<<ebt, 256, 0, stream>>>(src1, dst1, cur1, srcs1, E1,
                                   src2, dst2, cur2, srcs2, E2);

  // A fragments cols 0..127 + Hb = split(x)/bf16(x)
  cvt_k<<<(N * 64 + 255) / 256, 256, 0, stream>>>(x, Afh, Afl, Hb, N * 64);

  const int gx = (N + 127) / 128;
  const int ablocks = (N * 64 + 255) / 256;

  // Qt0 = x @ M -> Cbuf cols 128..255 (A steps 0..3, B = Mfrag)
  gemm_mfma<<<dim3(gx, 1), 256, 0, stream>>>(Afh, Afl, 4, Mfh, Mfl,
                                             128, Cbuf, 256, nullptr, N, TILES);

  for (int s = 0; s < 5; ++s) {
    const float* hsrc = (s == 0) ? x : Cbuf;
    const int ldh = (s == 0) ? D : 256;

    agg_k<<<ablocks, 256, 0, stream>>>(hsrc, ldh, Cbuf + 128, Hb,
                                       rp1, srcs1, rp2, srcs2, Afh, Afl, N);

    if (s == 4) {
      gemm_mfma<<<dim3(gx, 1), 256, 0, stream>>>(Afh, Afl, 12, Bfh, Bfl,
                                                 0, out, D, nullptr, N, TILES);
    } else {
      gemm_mfma<<<dim3(gx, 2), 256, 0, stream>>>(Afh, Afl, 12, Bfh, Bfl,
                                                 0, Cbuf, 256, Hb, N, TILES);
    }
  }
}